// Round 13
// baseline (11376.472 us; speedup 1.0000x reference)
//
#include <hip/hip_runtime.h>
#include <math.h>

// Problem constants (match reference)
#define B_   1024
#define NC   100
#define NN   101          // N = NC + 1
#define E_   128
#define T_   202          // 2*N
#define NEGV   -1.0e9
#define GAPTHR 4.0e-3f    // fp32-path error bound ~3e-4 -> 13x margin
#define INVSQE 0.08838834764831845f
#define INVSQED 0.08838834764831845

__device__ __forceinline__ float rdlane(float v, int l) {
    return __int_as_float(__builtin_amdgcn_readlane(__float_as_int(v), l));
}

// ---------------------------------------------------------------------------
// kernel 0: M = Wk2 @ Wout^T (128x128) into ws as fp64 (fallback) + fp32 (fast)
// ---------------------------------------------------------------------------
__global__ void k_weights(const float* __restrict__ Wk2,
                          const float* __restrict__ Wout,
                          double* __restrict__ M64,
                          float* __restrict__ M32) {
    int g = blockIdx.x;   // 0..127
    int e = threadIdx.x;  // 0..127
    const float* w2 = Wk2 + g * E_;
    const float* wo = Wout + e * E_;
    double acc = 0.0;
#pragma unroll 8
    for (int f = 0; f < E_; ++f) acc += (double)w2[f] * (double)wo[f];
    M64[g * E_ + e] = acc;
    M32[g * E_ + e] = (float)acc;
}

// ---------------------------------------------------------------------------
// Paired decoder: ONE 512-thread block decodes TWO batch elements.
// Waves 0-3 -> batch 2*bid (half 0); waves 4-7 -> batch 2*bid+1 (half 1).
// This bakes "2 batch elements per CU" into the block (scheduler can't deny
// it): while one half idles at a barrier-dependency, the other half's waves
// fill the SIMDs. Grid 512 -> 2 sequential rounds (vs round-7's 4).
// Per half: round-12 structure (wave = head pair; phases C/D split in half-
// chunks). Arrays rA[64]+rK2[64]; (512,1) cap=256 regs (round-2-proven).
// LDS ~119 KB: 2x(sV 52.2K overlaid by fp64 fallback + 5.4K scratch) + misc.
// Fallback is block-wide on (sTrig[0]|sTrig[1]); compute guarded per half,
// ALL threads execute every __syncthreads (no divergent-barrier hazard).
// ---------------------------------------------------------------------------
__global__ __launch_bounds__(512, 1)
void k_decode5(const float* __restrict__ depot_xy,
               const float* __restrict__ customer_xy,
               const float* __restrict__ demand,
               const float* __restrict__ node_emb,
               const float* __restrict__ graph_emb,
               const float* __restrict__ Wk1,
               const float* __restrict__ Wv,
               const float* __restrict__ Wq_fixed,
               const float* __restrict__ Wq_step,
               const double* __restrict__ M64,
               const float* __restrict__ M32,
               float* __restrict__ gks,          // [B][101][128] Kstep
               float* __restrict__ out)          // [2*B]: cost then ll
{
    __shared__ __align__(16) float sVbuf[2][102 * E_]; // 104.4 KB (pad row 101)
    __shared__ float  sFbuf[2][1344];                  // 10.8 KB scratch
    __shared__ float  sQfix32[2][E_];
    __shared__ float  sWqD32[E_];                      // batch-independent
    __shared__ float  sInvS[2][8];
    __shared__ float  sCoord[2][2 * NN];
    __shared__ float  sDem[2][NC];
    __shared__ float  sD[2];
    __shared__ double sCost[2], sLL[2];
    __shared__ float  sPosX[2], sPosY[2];
    __shared__ int    sPrev[2], sMaskDepot[2], sTrig[2], sOvf[2];
    __shared__ unsigned long long sVis0[2], sVis1[2];

    const int tid  = threadIdx.x;
    const int half = __builtin_amdgcn_readfirstlane(tid >> 8);    // 0..1
    const int t2   = tid & 255;
    const int lane = tid & 63;
    const int w    = __builtin_amdgcn_readfirstlane((tid >> 6) & 3); // wave-in-half
    const int k1   = lane + 64;
    const int k_lane = t2 & 127;
    const int cq   = __builtin_amdgcn_readfirstlane((tid >> 7) & 1); // 0..1

    const int bb = 2 * blockIdx.x + half;
    const float* emb = node_emb + (size_t)bb * NN * E_;

    float* sV  = sVbuf[half];
    float* fSc   = sFbuf[half];          // [8][104]
    float* fPart = sFbuf[half] + 832;    // [2][128]
    float* fPx   = sFbuf[half] + 1088;   // [2][128]
    // fallback fp64 views overlay this half's sV (17.8 KB < 52.2 KB)
    double* dUZ = (double*)sV;   // [128][8]
    double* dSc = dUZ + 1024;    // [8][101]
    double* dQ1 = dUZ + 1832;    // [128] q1, later xd[101]
    double* dGl = dUZ + 1960;    // [128]
    double* dVg = dUZ + 2088;    // [128]

    // ---------------- prologue (per half) ----------------
    if (t2 < E_) {
        const float* ge = graph_emb + (size_t)bb * E_;
        double acc = 0.0;
        for (int g = 0; g < E_; ++g)
            acc += (double)ge[g] * (double)Wq_fixed[g * E_ + t2];
        sQfix32[half][t2] = (float)acc;
        if (half == 0) sWqD32[t2] = Wq_step[128 * E_ + t2];
    }
    if (t2 < 2 * NN) {
        int k = t2 >> 1, xy = t2 & 1;
        sCoord[half][t2] = (k == 0) ? depot_xy[(size_t)bb * 2 + xy]
                                    : customer_xy[((size_t)bb * NC + (k - 1)) * 2 + xy];
    }
    if (t2 < NC) sDem[half][t2] = demand[(size_t)bb * NC + t2];
    if (t2 == 0) {
        sD[half] = 1.f; sPrev[half] = 0; sVis0[half] = 0ull; sVis1[half] = 0ull;
        sMaskDepot[half] = 1; sCost[half] = 0.0; sLL[half] = 0.0;
        sTrig[half] = 0; sOvf[half] = 0;
        sPosX[half] = depot_xy[(size_t)bb * 2 + 0];
        sPosY[half] = depot_xy[(size_t)bb * 2 + 1];
    }

    // V into LDS; Kstep into gks (global, L2-resident)
    for (int idx = t2; idx < NN * 32; idx += 256) {
        int k  = idx >> 5;
        int e4 = (idx & 31) * 4;
        const float* er = emb + (size_t)k * E_;
        float4 aV = {0.f, 0.f, 0.f, 0.f};
        float4 aK = {0.f, 0.f, 0.f, 0.f};
        for (int g = 0; g < E_; ++g) {
            float eg = er[g];
            float4 wv = *(const float4*)(Wv      + (size_t)g * E_ + e4);
            float4 wq = *(const float4*)(Wq_step + (size_t)g * E_ + e4);
            aV.x += eg * wv.x; aV.y += eg * wv.y;
            aV.z += eg * wv.z; aV.w += eg * wv.w;
            aK.x += eg * wq.x; aK.y += eg * wq.y;
            aK.z += eg * wq.z; aK.w += eg * wq.w;
        }
        *(float4*)(sV + (size_t)k * E_ + e4) = aV;
        *(float4*)(gks + ((size_t)bb * NN + k) * E_ + e4) = aK;
    }
    if (t2 < E_) sV[101 * E_ + t2] = 0.f;   // zero pad row (phase C reads it)

    // rA[64]: K1 fragments, head pair (2w,2w+1), nodes lane & lane+64
    float rA[64];
#pragma unroll
    for (int j = 0; j < 64; ++j) rA[j] = 0.f;
    {
        const float* er0 = emb + (size_t)lane * E_;
        const float* er1 = emb + (size_t)((k1 < NN) ? k1 : lane) * E_;
        const float  e1s = (k1 < NN) ? 1.f : 0.f;
        const float* w1b = Wk1 + w * 32;
        for (int g = 0; g < E_; ++g) {
            float a0 = er0[g];
            float a1 = er1[g] * e1s;
            const float* w1 = w1b + (size_t)g * E_;
#pragma unroll
            for (int j = 0; j < 32; ++j) {
                rA[j]      += a0 * w1[j];
                rA[32 + j] += a1 * w1[j];
            }
        }
    }

    // rK2[64]: K2t half-row (cols cq*64..cq*64+63) for node k_lane
    float rK2[64];
#pragma unroll
    for (int j = 0; j < 64; ++j) rK2[j] = 0.f;
    if (k_lane < NN) {
        const float* er = emb + (size_t)k_lane * E_;
        for (int g = 0; g < E_; ++g) {
            float eg = er[g];
            const float* mm = M32 + (size_t)g * E_ + cq * 64;
#pragma unroll
            for (int j = 0; j < 64; ++j) rK2[j] += eg * mm[j];
        }
    }
    __syncthreads();

    // ---------------- sequential decode loop ----------------
    for (int t = 0; t < T_; ++t) {
        // ---- B (per-wave, 2 heads): q1 slice from gks + scores + exp + sums --
        {
            int prev = sPrev[half];
            float Dv = sD[half];
            float q1v = 0.f;
            if (lane < 32) {
                int d_ = w * 32 + lane;
                float ksv = gks[((size_t)bb * NN + prev) * E_ + d_];
                q1v = (sQfix32[half][d_] + ksv + Dv * sWqD32[d_]) * 0.25f;
            }

            unsigned long long v0 = sVis0[half], v1 = sVis1[half];
            bool mk0, mk1;
            if (lane == 0) mk0 = (sMaskDepot[half] != 0);
            else {
                int c = lane - 1;   // 0..62 -> always in sVis0
                mk0 = ((v0 >> c) & 1ull) || (sDem[half][c] > Dv);
            }
            if (k1 < NN) {
                int c = k1 - 1;     // 63..99
                bool vis = (c < 64) ? ((v0 >> c) & 1ull)
                                    : ((v1 >> (c - 64)) & 1ull);
                mk1 = vis || (sDem[half][c] > Dv);
            } else mk1 = true;

            float s00 = 0.f, s01 = 0.f, s10 = 0.f, s11 = 0.f;
#pragma unroll
            for (int j = 0; j < 16; ++j) {
                float qd = rdlane(q1v, j);
                s00 += rA[j] * qd;
                s01 += rA[32 + j] * qd;
            }
#pragma unroll
            for (int j = 16; j < 32; ++j) {
                float qd = rdlane(q1v, j);
                s10 += rA[j] * qd;
                s11 += rA[32 + j] * qd;
            }
            bool ovf = (!mk0 && (s00 > 80.f || s10 > 80.f)) ||
                       (!mk1 && (s01 > 80.f || s11 > 80.f));
            if (__any(ovf)) { if (lane == 0) sOvf[half] = 1; }
            float w00 = mk0 ? 0.f : expf(fminf(s00, 80.f));
            float w01 = mk1 ? 0.f : expf(fminf(s01, 80.f));
            float w10 = mk0 ? 0.f : expf(fminf(s10, 80.f));
            float w11 = mk1 ? 0.f : expf(fminf(s11, 80.f));
            int h0 = 2 * w, h1 = h0 + 1;
            fSc[h0 * 104 + lane] = w00;
            fSc[h1 * 104 + lane] = w10;
            if (k1 < 104) {
                fSc[h0 * 104 + k1] = w01;
                fSc[h1 * 104 + k1] = w11;
            }
            float ws0 = w00 + w01, ws1 = w10 + w11;
#pragma unroll
            for (int m = 32; m >= 1; m >>= 1) {
                ws0 += __shfl_xor(ws0, m);
                ws1 += __shfl_xor(ws1, m);
            }
            if (lane == 0) { sInvS[half][h0] = 1.0f / ws0; sInvS[half][h1] = 1.0f / ws1; }
        }
        __syncthreads();

        // ---- C: glimpse half-partials (51 nodes per half-chunk; pad row 0) --
        {
            int e = k_lane, h = e >> 4;
            int kb = cq * 51;
            const float* sc = fSc + h * 104 + kb;
            const float* vv = sV + (size_t)kb * E_ + e;
            float p = 0.f;
#pragma unroll
            for (int j = 0; j < 51; ++j) p += sc[j] * vv[j * E_];
            fPart[cq * E_ + e] = p;
        }
        __syncthreads();

        // ---- D: logit half-dots via readlane ----
        {
            int e = cq * 64 + lane;
            float glv = (fPart[e] + fPart[128 + e]) * sInvS[half][e >> 4];
            float x = 0.f;
#pragma unroll
            for (int j = 0; j < 64; ++j) x += rK2[j] * rdlane(glv, j);
            if (k_lane < NN) fPx[cq * E_ + k_lane] = x;
        }
        __syncthreads();

        // ---- E: per-half top-2 argmax, gap test, commit-or-trigger ----
        if (t2 < 64) {
            int kA = t2, kB = t2 + 64;
            float xA = (fPx[kA] + fPx[128 + kA]) * INVSQE;
            bool mk1;
            if (kA == 0) mk1 = (sMaskDepot[half] != 0);
            else {
                int c = kA - 1;
                bool vis = (c < 64) ? ((sVis0[half] >> c) & 1ull)
                                    : ((sVis1[half] >> (c - 64)) & 1ull);
                mk1 = vis || (sDem[half][c] > sD[half]);
            }
            float xB = -3.0e38f; bool mk2 = true;
            if (kB < NN) {
                xB = (fPx[kB] + fPx[128 + kB]) * INVSQE;
                int c = kB - 1;
                bool vis = (c < 64) ? ((sVis0[half] >> c) & 1ull)
                                    : ((sVis1[half] >> (c - 64)) & 1ull);
                mk2 = vis || (sDem[half][c] > sD[half]);
            }
            float a1v = mk1 ? -3.0e38f : xA;
            float a2v = mk2 ? -3.0e38f : xB;
            float m1, m2; int mi;
            if (a2v > a1v) { m1 = a2v; m2 = a1v; mi = kB; }
            else           { m1 = a1v; m2 = a2v; mi = kA; }
            float ls = 0.f;
            if (!mk1)              ls += expf(10.f * tanhf(xA));
            if (kB < NN && !mk2)   ls += expf(10.f * tanhf(xB));
#pragma unroll
            for (int off = 32; off > 0; off >>= 1) {
                float om1 = __shfl_xor(m1, off);
                float om2 = __shfl_xor(m2, off);
                float os  = __shfl_xor(ls, off);
                int   omi = __shfl_xor(mi, off);
                ls += os;
                if (om1 > m1 || (om1 == m1 && omi < mi)) {
                    m2 = fmaxf(m1, om2); m1 = om1; mi = omi;
                } else {
                    m2 = fmaxf(m2, om1);
                }
            }
            if ((tid & 63) == 0) {
                float gap = m1 - m2;
                bool trig = !(gap >= GAPTHR) || (sOvf[half] != 0);   // NaN-safe
                sOvf[half] = 0;
                if (trig) {
                    sTrig[half] = 1;
                } else {
                    float lsel = 10.f * tanhf(m1);
                    float logp = lsel - logf(ls);
                    int nxt = mi;
                    sLL[half] += (double)logp;
                    bool isdep = (nxt == 0);
                    if (isdep) {
                        sD[half] = 1.0f;
                    } else {
                        int c = nxt - 1;
                        sD[half] = sD[half] - sDem[half][c];
                        if (c < 64) sVis0[half] |= (1ull << c);
                        else        sVis1[half] |= (1ull << (c - 64));
                    }
                    bool allv = (sVis0[half] == 0xFFFFFFFFFFFFFFFFull) &&
                                (sVis1[half] == 0x0000000FFFFFFFFFull);
                    sMaskDepot[half] = (isdep && !allv) ? 1 : 0;
                    sPrev[half] = nxt;
                    float cx = sCoord[half][2 * nxt], cy = sCoord[half][2 * nxt + 1];
                    double dx = (double)cx - (double)sPosX[half];
                    double dy = (double)cy - (double)sPosY[half];
                    sCost[half] += sqrt(dx * dx + dy * dy + 1e-10);
                    sPosX[half] = cx; sPosY[half] = cy;
                }
            }
        }
        __syncthreads();

        // ---- Fallback (block-wide entry, per-half compute): exact fp64 ----
        if (sTrig[0] | sTrig[1]) {
            const bool myTrig = (sTrig[half] != 0);

            if (myTrig && t2 < E_) {
                const float* ge = graph_emb + (size_t)bb * E_;
                const float* ep = emb + (size_t)sPrev[half] * E_;
                double qf = 0.0, ks = 0.0;
#pragma clang loop unroll(disable)
                for (int g = 0; g < E_; ++g) {
                    qf += (double)ge[g] * (double)Wq_fixed[(size_t)g * E_ + t2];
                    ks += (double)ep[g] * (double)Wq_step[(size_t)g * E_ + t2];
                }
                dQ1[t2] = (qf + ks + (double)sD[half] * (double)Wq_step[128 * E_ + t2]) * 0.25;
            }
            __syncthreads();
            if (myTrig)
            for (int idx = t2; idx < 1024; idx += 256) {
                int g = idx >> 3, hh = idx & 7;
                double u = 0.0;
#pragma clang loop unroll(disable)
                for (int d = 0; d < 16; ++d)
                    u += dQ1[hh * 16 + d] * (double)Wk1[(size_t)g * E_ + hh * 16 + d];
                dUZ[idx] = u;
            }
            __syncthreads();
            if (myTrig)
            for (int idx = t2; idx < 1024; idx += 256) {
                int k = idx & 127, hh = idx >> 7;
                if (k < NN) {
                    bool mk;
                    if (k == 0) mk = (sMaskDepot[half] != 0);
                    else {
                        int c = k - 1;
                        bool vis = (c < 64) ? ((sVis0[half] >> c) & 1ull)
                                            : ((sVis1[half] >> (c - 64)) & 1ull);
                        mk = vis || (sDem[half][c] > sD[half]);
                    }
                    if (mk) dSc[hh * NN + k] = NEGV;
                    else {
                        const float* ek = emb + (size_t)k * E_;
                        double s = 0.0;
#pragma clang loop unroll(disable)
                        for (int g = 0; g < E_; ++g)
                            s += (double)ek[g] * dUZ[g * 8 + hh];
                        dSc[hh * NN + k] = s;
                    }
                }
            }
            __syncthreads();
            // per-head softmax: two passes, wave-aligned within the half
            if (myTrig)
            for (int base = 0; base < 512; base += 256) {
                int idx = base + t2;
                int hh = idx >> 6, ln = idx & 63;
                int kA = ln, kB = ln + 64;
                double v1 = dSc[hh * NN + kA];
                double v2 = (kB < NN) ? dSc[hh * NN + kB] : -1.0e300;
                double m = fmax(v1, v2);
#pragma unroll
                for (int off = 32; off > 0; off >>= 1)
                    m = fmax(m, __shfl_xor(m, off));
                double e1 = exp(v1 - m);
                double e2 = (kB < NN) ? exp(v2 - m) : 0.0;
                double s = e1 + e2;
#pragma unroll
                for (int off = 32; off > 0; off >>= 1)
                    s += __shfl_xor(s, off);
                double inv = 1.0 / s;
                dSc[hh * NN + kA] = e1 * inv;
                if (kB < NN) dSc[hh * NN + kB] = e2 * inv;
            }
            __syncthreads();
            if (myTrig)
            for (int idx = t2; idx < 1024; idx += 256) {
                int g = idx >> 3, hh = idx & 7;
                double z = 0.0;
#pragma clang loop unroll(disable)
                for (int k = 0; k < NN; ++k)
                    z += dSc[hh * NN + k] * (double)emb[(size_t)k * E_ + g];
                dUZ[idx] = z;
            }
            __syncthreads();
            if (myTrig && t2 < E_) {
                int hh = t2 >> 4;
                double g2 = 0.0;
#pragma clang loop unroll(disable)
                for (int g = 0; g < E_; ++g)
                    g2 += dUZ[g * 8 + hh] * (double)Wv[(size_t)g * E_ + t2];
                dGl[t2] = g2;
            }
            __syncthreads();
            if (myTrig && t2 < E_) {
                double v = 0.0;
#pragma clang loop unroll(disable)
                for (int e = 0; e < E_; ++e)
                    v += dGl[e] * M64[(size_t)t2 * E_ + e];
                dVg[t2] = v;
            }
            __syncthreads();
            if (myTrig && t2 < NN) {
                const float* ek = emb + (size_t)t2 * E_;
                double x = 0.0;
#pragma clang loop unroll(disable)
                for (int g = 0; g < E_; ++g)
                    x += (double)ek[g] * dVg[g];
                dQ1[t2] = x * INVSQED;
            }
            __syncthreads();
            if (myTrig && t2 < 64) {
                int kA = t2, kB = t2 + 64;
                double x1 = dQ1[kA];
                bool mk1;
                if (kA == 0) mk1 = (sMaskDepot[half] != 0);
                else {
                    int c = kA - 1;
                    bool vis = (c < 64) ? ((sVis0[half] >> c) & 1ull)
                                        : ((sVis1[half] >> (c - 64)) & 1ull);
                    mk1 = vis || (sDem[half][c] > sD[half]);
                }
                double x2 = 0.0; bool mk2 = true;
                if (kB < NN) {
                    x2 = dQ1[kB];
                    int c = kB - 1;
                    bool vis = (c < 64) ? ((sVis0[half] >> c) & 1ull)
                                        : ((sVis1[half] >> (c - 64)) & 1ull);
                    mk2 = vis || (sDem[half][c] > sD[half]);
                }
                double a1 = mk1 ? -1.0e300 : x1;
                double a2 = (kB < NN && !mk2) ? x2 : -1.0e300;
                double mv; int mi;
                if (a1 >= a2) { mv = a1; mi = kA; } else { mv = a2; mi = kB; }
#pragma unroll
                for (int off = 32; off > 0; off >>= 1) {
                    double ov = __shfl_xor(mv, off);
                    int    oi = __shfl_xor(mi, off);
                    if (ov > mv || (ov == mv && oi < mi)) { mv = ov; mi = oi; }
                }
                double lmax = 10.0 * tanh(mv);
                double l1 = mk1 ? NEGV : 10.0 * tanh(x1);
                double l2 = (kB < NN) ? (mk2 ? NEGV : 10.0 * tanh(x2)) : 0.0;
                double s = exp(l1 - lmax) + ((kB < NN) ? exp(l2 - lmax) : 0.0);
#pragma unroll
                for (int off = 32; off > 0; off >>= 1)
                    s += __shfl_xor(s, off);
                if ((tid & 63) == 0) {
                    int nxt = mi;
                    sLL[half] += -log(s);
                    bool isdep = (nxt == 0);
                    if (isdep) {
                        sD[half] = 1.0f;
                    } else {
                        int c = nxt - 1;
                        sD[half] = sD[half] - sDem[half][c];
                        if (c < 64) sVis0[half] |= (1ull << c);
                        else        sVis1[half] |= (1ull << (c - 64));
                    }
                    bool allv = (sVis0[half] == 0xFFFFFFFFFFFFFFFFull) &&
                                (sVis1[half] == 0x0000000FFFFFFFFFull);
                    sMaskDepot[half] = (isdep && !allv) ? 1 : 0;
                    sPrev[half] = nxt;
                    float cx = sCoord[half][2 * nxt], cy = sCoord[half][2 * nxt + 1];
                    double dx = (double)cx - (double)sPosX[half];
                    double dy = (double)cy - (double)sPosY[half];
                    sCost[half] += sqrt(dx * dx + dy * dy + 1e-10);
                    sPosX[half] = cx; sPosY[half] = cy;
                    sTrig[half] = 0;
                }
            }
            __syncthreads();

            // Restage this half's V (overlay destroyed rows 0..34)
            if (myTrig) {
                for (int idx = t2; idx < NN * 32; idx += 256) {
                    int k  = idx >> 5;
                    int e4 = (idx & 31) * 4;
                    const float* er = emb + (size_t)k * E_;
                    float4 aV = {0.f, 0.f, 0.f, 0.f};
                    for (int g = 0; g < E_; ++g) {
                        float eg = er[g];
                        float4 wv = *(const float4*)(Wv + (size_t)g * E_ + e4);
                        aV.x += eg * wv.x; aV.y += eg * wv.y;
                        aV.z += eg * wv.z; aV.w += eg * wv.w;
                    }
                    *(float4*)(sV + (size_t)k * E_ + e4) = aV;
                }
            }
            __syncthreads();
        }
    }

    if (t2 == 0) {
        double dx = (double)sCoord[half][0] - (double)sPosX[half];
        double dy = (double)sCoord[half][1] - (double)sPosY[half];
        out[bb]      = (float)(sCost[half] + sqrt(dx * dx + dy * dy + 1e-10));
        out[B_ + bb] = (float)sLL[half];
    }
}

// ---------------------------------------------------------------------------
// v7 safety-net decoder (round-7 kernel, verbatim; ~4080 us) for ws too small.
// ---------------------------------------------------------------------------
__global__ __launch_bounds__(512, 2)
void k_decode_v7(const float* __restrict__ depot_xy,
                 const float* __restrict__ customer_xy,
                 const float* __restrict__ demand,
                 const float* __restrict__ node_emb,
                 const float* __restrict__ graph_emb,
                 const float* __restrict__ Wk1,
                 const float* __restrict__ Wv,
                 const float* __restrict__ Wq_fixed,
                 const float* __restrict__ Wq_step,
                 const double* __restrict__ M64,
                 const float* __restrict__ M32,
                 float* __restrict__ out)
{
    __shared__ float  sKs[NN * E_];
    __shared__ float  sV [NN * E_];
    __shared__ double sU[2224];
    __shared__ double sQfix64[E_];
    __shared__ double sWqD64[E_];
    __shared__ float  sQfix32[E_];
    __shared__ float  sWqD32[E_];
    __shared__ float  sInvS[8];
    __shared__ float  sCoord[2 * NN];
    __shared__ float  sDem[NC];
    __shared__ float  sD;
    __shared__ double sCost, sLL;
    __shared__ float  sPosX, sPosY;
    __shared__ int    sPrev, sMaskDepot, sTrig, sOvf;
    __shared__ unsigned long long sVis0, sVis1;

    float* fSc   = (float*)sU;
    float* fPart = (float*)sU + 832;
    float* fPx   = (float*)sU + 1344;
    double* dUZ = sU;
    double* dSc = sU + 1024;
    double* dQ1 = sU + 1832;
    double* dGl = sU + 1960;
    double* dVg = sU + 2088;

    const int b      = blockIdx.x;
    const int tid    = threadIdx.x;
    const int lane   = tid & 63;
    const int h      = __builtin_amdgcn_readfirstlane(tid >> 6);
    const int k1     = lane + 64;
    const int k_lane = tid & 127;
    const int q2u    = __builtin_amdgcn_readfirstlane(tid >> 7);
    const int e0     = q2u * 32;
    const int kb     = q2u * 26;

    const float* emb = node_emb + (size_t)b * NN * E_;

    if (tid < E_) {
        const float* ge = graph_emb + (size_t)b * E_;
        double acc = 0.0;
        for (int g = 0; g < E_; ++g)
            acc += (double)ge[g] * (double)Wq_fixed[g * E_ + tid];
        sQfix64[tid] = acc;
        sQfix32[tid] = (float)acc;
        sWqD64[tid]  = (double)Wq_step[128 * E_ + tid];
        sWqD32[tid]  = Wq_step[128 * E_ + tid];
    }
    if (tid < 2 * NN) {
        int k = tid >> 1, xy = tid & 1;
        sCoord[tid] = (k == 0) ? depot_xy[(size_t)b * 2 + xy]
                               : customer_xy[((size_t)b * NC + (k - 1)) * 2 + xy];
    }
    if (tid < NC) sDem[tid] = demand[(size_t)b * NC + tid];
    if (tid == 0) {
        sD = 1.f; sPrev = 0; sVis0 = 0ull; sVis1 = 0ull;
        sMaskDepot = 1; sCost = 0.0; sLL = 0.0; sTrig = 0; sOvf = 0;
        sPosX = depot_xy[(size_t)b * 2 + 0];
        sPosY = depot_xy[(size_t)b * 2 + 1];
    }

    for (int idx = tid; idx < NN * 32; idx += 512) {
        int k  = idx >> 5;
        int e4 = (idx & 31) * 4;
        const float* er = emb + (size_t)k * E_;
        float4 aV = {0.f, 0.f, 0.f, 0.f};
        float4 aK = {0.f, 0.f, 0.f, 0.f};
        for (int g = 0; g < E_; ++g) {
            float eg = er[g];
            float4 wv = *(const float4*)(Wv      + (size_t)g * E_ + e4);
            float4 wq = *(const float4*)(Wq_step + (size_t)g * E_ + e4);
            aV.x += eg * wv.x; aV.y += eg * wv.y;
            aV.z += eg * wv.z; aV.w += eg * wv.w;
            aK.x += eg * wq.x; aK.y += eg * wq.y;
            aK.z += eg * wq.z; aK.w += eg * wq.w;
        }
        *(float4*)(sV  + (size_t)k * E_ + e4) = aV;
        *(float4*)(sKs + (size_t)k * E_ + e4) = aK;
    }

    float rA[32];
#pragma unroll
    for (int j = 0; j < 32; ++j) rA[j] = 0.f;
    {
        const float* er0 = emb + (size_t)lane * E_;
        const float* er1 = emb + (size_t)((k1 < NN) ? k1 : lane) * E_;
        const float  e1s = (k1 < NN) ? 1.f : 0.f;
        const float* w1b = Wk1 + h * 16;
        for (int g = 0; g < E_; ++g) {
            float a0 = er0[g];
            float a1 = er1[g] * e1s;
            const float* w1 = w1b + (size_t)g * E_;
#pragma unroll
            for (int d = 0; d < 16; ++d) {
                rA[d]      += a0 * w1[d];
                rA[16 + d] += a1 * w1[d];
            }
        }
    }

    float rK2[32];
#pragma unroll
    for (int j = 0; j < 32; ++j) rK2[j] = 0.f;
    if (k_lane < NN) {
        const float* er = emb + (size_t)k_lane * E_;
        for (int g = 0; g < E_; ++g) {
            float eg = er[g];
            const float* mm = M32 + (size_t)g * E_ + e0;
#pragma unroll
            for (int j = 0; j < 32; ++j) rK2[j] += eg * mm[j];
        }
    }
    __syncthreads();

    for (int t = 0; t < T_; ++t) {
        {
            int prev = sPrev;
            float Dv = sD;
            int d_ = h * 16 + (lane & 15);
            float q1v = (sQfix32[d_] + sKs[(size_t)prev * E_ + d_]
                         + Dv * sWqD32[d_]) * 0.25f;

            unsigned long long v0 = sVis0, v1 = sVis1;
            bool mk0, mk1;
            if (lane == 0) mk0 = (sMaskDepot != 0);
            else {
                int c = lane - 1;
                mk0 = ((v0 >> c) & 1ull) || (sDem[c] > Dv);
            }
            if (k1 < NN) {
                int c = k1 - 1;
                bool vis = (c < 64) ? ((v0 >> c) & 1ull)
                                    : ((v1 >> (c - 64)) & 1ull);
                mk1 = vis || (sDem[c] > Dv);
            } else mk1 = true;

            float s0 = 0.f, s1 = 0.f;
#pragma unroll
            for (int d = 0; d < 16; ++d) {
                float qd = rdlane(q1v, d);
                s0 += rA[d] * qd;
                s1 += rA[16 + d] * qd;
            }
            bool ovf = (!mk0 && s0 > 80.f) || (!mk1 && s1 > 80.f);
            if (__any(ovf)) { if (lane == 0) sOvf = 1; }
            float w0 = mk0 ? 0.f : expf(fminf(s0, 80.f));
            float w1 = mk1 ? 0.f : expf(fminf(s1, 80.f));
            fSc[h * 104 + lane] = w0;
            if (k1 < 104) fSc[h * 104 + k1] = w1;
            float wsum = w0 + w1;
#pragma unroll
            for (int m = 32; m >= 1; m >>= 1) wsum += __shfl_xor(wsum, m);
            if (lane == 0) sInvS[h] = 1.0f / wsum;
        }
        __syncthreads();

        {
            int e = k_lane, hh = e >> 4;
            const float* sc = fSc + hh * 104 + kb;
            const float* vv = sV + (size_t)kb * E_ + e;
            float p = 0.f;
#pragma unroll
            for (int j = 0; j < 26; ++j) p += sc[j] * vv[j * E_];
            fPart[q2u * E_ + e] = p;
        }
        __syncthreads();

        {
            int ee = e0 + (tid & 31);
            float glv = (fPart[ee] + fPart[128 + ee] + fPart[256 + ee]
                         + fPart[384 + ee]) * sInvS[ee >> 4];
            float x = 0.f;
#pragma unroll
            for (int j = 0; j < 32; ++j) x += rK2[j] * rdlane(glv, j);
            if (k_lane < NN) fPx[q2u * E_ + k_lane] = x;
        }
        __syncthreads();

        if (tid < 64) {
            int kA = tid, kB = tid + 64;
            float xA = (fPx[kA] + fPx[128 + kA] + fPx[256 + kA] + fPx[384 + kA]) * INVSQE;
            bool mk1;
            if (kA == 0) mk1 = (sMaskDepot != 0);
            else {
                int c = kA - 1;
                bool vis = (c < 64) ? ((sVis0 >> c) & 1ull) : ((sVis1 >> (c - 64)) & 1ull);
                mk1 = vis || (sDem[c] > sD);
            }
            float xB = -3.0e38f; bool mk2 = true;
            if (kB < NN) {
                xB = (fPx[kB] + fPx[128 + kB] + fPx[256 + kB] + fPx[384 + kB]) * INVSQE;
                int c = kB - 1;
                bool vis = (c < 64) ? ((sVis0 >> c) & 1ull) : ((sVis1 >> (c - 64)) & 1ull);
                mk2 = vis || (sDem[c] > sD);
            }
            float a1v = mk1 ? -3.0e38f : xA;
            float a2v = mk2 ? -3.0e38f : xB;
            float m1, m2; int mi;
            if (a2v > a1v) { m1 = a2v; m2 = a1v; mi = kB; }
            else           { m1 = a1v; m2 = a2v; mi = kA; }
            float ls = 0.f;
            if (!mk1)              ls += expf(10.f * tanhf(xA));
            if (kB < NN && !mk2)   ls += expf(10.f * tanhf(xB));
#pragma unroll
            for (int off = 32; off > 0; off >>= 1) {
                float om1 = __shfl_xor(m1, off);
                float om2 = __shfl_xor(m2, off);
                float os  = __shfl_xor(ls, off);
                int   omi = __shfl_xor(mi, off);
                ls += os;
                if (om1 > m1 || (om1 == m1 && omi < mi)) {
                    m2 = fmaxf(m1, om2); m1 = om1; mi = omi;
                } else {
                    m2 = fmaxf(m2, om1);
                }
            }
            if (tid == 0) {
                float gap = m1 - m2;
                bool trig = !(gap >= GAPTHR) || (sOvf != 0);
                sOvf = 0;
                if (trig) {
                    sTrig = 1;
                } else {
                    float lsel = 10.f * tanhf(m1);
                    float logp = lsel - logf(ls);
                    int nxt = mi;
                    sLL += (double)logp;
                    bool isdep = (nxt == 0);
                    if (isdep) {
                        sD = 1.0f;
                    } else {
                        int c = nxt - 1;
                        sD = sD - sDem[c];
                        if (c < 64) sVis0 |= (1ull << c);
                        else        sVis1 |= (1ull << (c - 64));
                    }
                    bool allv = (sVis0 == 0xFFFFFFFFFFFFFFFFull) &&
                                (sVis1 == 0x0000000FFFFFFFFFull);
                    sMaskDepot = (isdep && !allv) ? 1 : 0;
                    sPrev = nxt;
                    float cx = sCoord[2 * nxt], cy = sCoord[2 * nxt + 1];
                    double dx = (double)cx - (double)sPosX;
                    double dy = (double)cy - (double)sPosY;
                    sCost += sqrt(dx * dx + dy * dy + 1e-10);
                    sPosX = cx; sPosY = cy;
                }
            }
        }
        __syncthreads();

        if (sTrig) {
            if (tid < E_) {
                const float* ep = emb + (size_t)sPrev * E_;
                double ks = 0.0;
                for (int g = 0; g < E_; ++g)
                    ks += (double)ep[g] * (double)Wq_step[(size_t)g * E_ + tid];
                dQ1[tid] = (sQfix64[tid] + ks + (double)sD * sWqD64[tid]) * 0.25;
            }
            __syncthreads();
            for (int idx = tid; idx < 1024; idx += 512) {
                int g = idx >> 3, hh = idx & 7;
                double u = 0.0;
                for (int d = 0; d < 16; ++d)
                    u += dQ1[hh * 16 + d] * (double)Wk1[(size_t)g * E_ + hh * 16 + d];
                dUZ[idx] = u;
            }
            __syncthreads();
            for (int idx = tid; idx < 1024; idx += 512) {
                int k = idx & 127, hh = idx >> 7;
                if (k < NN) {
                    bool mk;
                    if (k == 0) mk = (sMaskDepot != 0);
                    else {
                        int c = k - 1;
                        bool vis = (c < 64) ? ((sVis0 >> c) & 1ull) : ((sVis1 >> (c - 64)) & 1ull);
                        mk = vis || (sDem[c] > sD);
                    }
                    if (mk) dSc[hh * NN + k] = NEGV;
                    else {
                        const float* ek = emb + (size_t)k * E_;
                        double s = 0.0;
                        for (int g = 0; g < E_; ++g)
                            s += (double)ek[g] * dUZ[g * 8 + hh];
                        dSc[hh * NN + k] = s;
                    }
                }
            }
            __syncthreads();
            {
                int hh = tid >> 6, ln = tid & 63;
                int kA = ln, kB = ln + 64;
                double v1 = dSc[hh * NN + kA];
                double v2 = (kB < NN) ? dSc[hh * NN + kB] : -1.0e300;
                double m = fmax(v1, v2);
#pragma unroll
                for (int off = 32; off > 0; off >>= 1)
                    m = fmax(m, __shfl_xor(m, off));
                double e1 = exp(v1 - m);
                double e2 = (kB < NN) ? exp(v2 - m) : 0.0;
                double s = e1 + e2;
#pragma unroll
                for (int off = 32; off > 0; off >>= 1)
                    s += __shfl_xor(s, off);
                double inv = 1.0 / s;
                dSc[hh * NN + kA] = e1 * inv;
                if (kB < NN) dSc[hh * NN + kB] = e2 * inv;
            }
            __syncthreads();
            for (int idx = tid; idx < 1024; idx += 512) {
                int g = idx >> 3, hh = idx & 7;
                double z = 0.0;
                for (int k = 0; k < NN; ++k)
                    z += dSc[hh * NN + k] * (double)emb[(size_t)k * E_ + g];
                dUZ[idx] = z;
            }
            __syncthreads();
            if (tid < E_) {
                int hh = tid >> 4;
                double g2 = 0.0;
                for (int g = 0; g < E_; ++g)
                    g2 += dUZ[g * 8 + hh] * (double)Wv[(size_t)g * E_ + tid];
                dGl[tid] = g2;
            }
            __syncthreads();
            if (tid < E_) {
                double v = 0.0;
                for (int e = 0; e < E_; ++e)
                    v += dGl[e] * M64[(size_t)tid * E_ + e];
                dVg[tid] = v;
            }
            __syncthreads();
            if (tid < NN) {
                const float* ek = emb + (size_t)tid * E_;
                double x = 0.0;
                for (int g = 0; g < E_; ++g)
                    x += (double)ek[g] * dVg[g];
                dQ1[tid] = x * INVSQED;
            }
            __syncthreads();
            if (tid < 64) {
                int kA = tid, kB = tid + 64;
                double x1 = dQ1[kA];
                bool mk1;
                if (kA == 0) mk1 = (sMaskDepot != 0);
                else {
                    int c = kA - 1;
                    bool vis = (c < 64) ? ((sVis0 >> c) & 1ull) : ((sVis1 >> (c - 64)) & 1ull);
                    mk1 = vis || (sDem[c] > sD);
                }
                double x2 = 0.0; bool mk2 = true;
                if (kB < NN) {
                    x2 = dQ1[kB];
                    int c = kB - 1;
                    bool vis = (c < 64) ? ((sVis0 >> c) & 1ull) : ((sVis1 >> (c - 64)) & 1ull);
                    mk2 = vis || (sDem[c] > sD);
                }
                double a1 = mk1 ? -1.0e300 : x1;
                double a2 = (kB < NN && !mk2) ? x2 : -1.0e300;
                double mv; int mi;
                if (a1 >= a2) { mv = a1; mi = kA; } else { mv = a2; mi = kB; }
#pragma unroll
                for (int off = 32; off > 0; off >>= 1) {
                    double ov = __shfl_xor(mv, off);
                    int    oi = __shfl_xor(mi, off);
                    if (ov > mv || (ov == mv && oi < mi)) { mv = ov; mi = oi; }
                }
                double lmax = 10.0 * tanh(mv);
                double l1 = mk1 ? NEGV : 10.0 * tanh(x1);
                double l2 = (kB < NN) ? (mk2 ? NEGV : 10.0 * tanh(x2)) : 0.0;
                double s = exp(l1 - lmax) + ((kB < NN) ? exp(l2 - lmax) : 0.0);
#pragma unroll
                for (int off = 32; off > 0; off >>= 1)
                    s += __shfl_xor(s, off);
                if (tid == 0) {
                    int nxt = mi;
                    sLL += -log(s);
                    bool isdep = (nxt == 0);
                    if (isdep) {
                        sD = 1.0f;
                    } else {
                        int c = nxt - 1;
                        sD = sD - sDem[c];
                        if (c < 64) sVis0 |= (1ull << c);
                        else        sVis1 |= (1ull << (c - 64));
                    }
                    bool allv = (sVis0 == 0xFFFFFFFFFFFFFFFFull) &&
                                (sVis1 == 0x0000000FFFFFFFFFull);
                    sMaskDepot = (isdep && !allv) ? 1 : 0;
                    sPrev = nxt;
                    float cx = sCoord[2 * nxt], cy = sCoord[2 * nxt + 1];
                    double dx = (double)cx - (double)sPosX;
                    double dy = (double)cy - (double)sPosY;
                    sCost += sqrt(dx * dx + dy * dy + 1e-10);
                    sPosX = cx; sPosY = cy;
                    sTrig = 0;
                }
            }
            __syncthreads();
        }
    }

    if (tid == 0) {
        double dx = (double)sCoord[0] - (double)sPosX;
        double dy = (double)sCoord[1] - (double)sPosY;
        out[b]      = (float)(sCost + sqrt(dx * dx + dy * dy + 1e-10));
        out[B_ + b] = (float)sLL;
    }
}

// ---------------------------------------------------------------------------
extern "C" void kernel_launch(void* const* d_in, const int* in_sizes, int n_in,
                              void* d_out, int out_size, void* d_ws, size_t ws_size,
                              hipStream_t stream) {
    const float* depot = (const float*)d_in[0];
    const float* cust  = (const float*)d_in[1];
    const float* dem   = (const float*)d_in[2];
    const float* nemb  = (const float*)d_in[3];
    const float* gemb  = (const float*)d_in[4];
    const float* Wk1   = (const float*)d_in[5];
    const float* Wv    = (const float*)d_in[6];
    const float* Wk2   = (const float*)d_in[7];
    const float* Wqf   = (const float*)d_in[8];
    const float* Wout  = (const float*)d_in[9];
    const float* Wqs   = (const float*)d_in[10];
    float*  out = (float*)d_out;

    double* M64 = (double*)d_ws;                       // 128 KB @ 0
    float*  M32 = (float*)((char*)d_ws + 131072);      // 64 KB  @ 128K

    // Kstep workspace: [B][101][128] fp32 = 52.95 MB (proven to fit, round 8)
    const size_t gks_off   = 196608;
    const size_t gks_bytes = (size_t)B_ * NN * E_ * sizeof(float);
    float* gks = (ws_size >= gks_off + gks_bytes)
               ? (float*)((char*)d_ws + gks_off) : nullptr;

    k_weights<<<dim3(128), dim3(128), 0, stream>>>(Wk2, Wout, M64, M32);
    if (gks) {
        k_decode5<<<dim3(B_ / 2), dim3(512), 0, stream>>>(depot, cust, dem, nemb,
                                                          gemb, Wk1, Wv, Wqf, Wqs,
                                                          M64, M32, gks, out);
    } else {
        k_decode_v7<<<dim3(B_), dim3(512), 0, stream>>>(depot, cust, dem, nemb,
                                                        gemb, Wk1, Wv, Wqf, Wqs,
                                                        M64, M32, out);
    }
}

// Round 14
// 3576.534 us; speedup vs baseline: 3.1809x; 3.1809x over previous
//
#include <hip/hip_runtime.h>
#include <math.h>

// Problem constants (match reference)
#define B_   1024
#define NC   100
#define NN   101          // N = NC + 1
#define E_   128
#define T_   202          // 2*N
#define NEGV   -1.0e9
#define GAPTHR 1.0e-3f    // fp32-path error ~1e-4 -> 10x margin.
                          // (was 4e-3: same decisions, ~4x more fp64 fallbacks;
                          //  round-14 A/B: fallback frequency hypothesis)
#define INVSQE 0.08838834764831845f
#define INVSQED 0.08838834764831845

__device__ __forceinline__ float rdlane(float v, int l) {
    return __int_as_float(__builtin_amdgcn_readlane(__float_as_int(v), l));
}

// ---------------------------------------------------------------------------
// kernel 0: M = Wk2 @ Wout^T (128x128) into ws as fp64 (fallback) + fp32 (fast)
// ---------------------------------------------------------------------------
__global__ void k_weights(const float* __restrict__ Wk2,
                          const float* __restrict__ Wout,
                          double* __restrict__ M64,
                          float* __restrict__ M32) {
    int g = blockIdx.x;   // 0..127
    int e = threadIdx.x;  // 0..127
    const float* w2 = Wk2 + g * E_;
    const float* wo = Wout + e * E_;
    double acc = 0.0;
#pragma unroll 8
    for (int f = 0; f < E_; ++f) acc += (double)w2[f] * (double)wo[f];
    M64[g * E_ + e] = acc;
    M32[g * E_ + e] = (float)acc;
}

// ---------------------------------------------------------------------------
// Main decoder (round-7 structure, verbatim; only GAPTHR changed).
// 1 block / batch element, 512 threads (8 waves).
// Arrays rA[32]+rK2[32] (=64 floats) -> no spill at the compiler's 128-VGPR
// point. Scores via reg-K1 + readlane; glimpse via LDS sV; logits via
// reg-K2t + readlane. 4 barriers/step.
// Exact fp64 fallback on near-tie argmax (gap < GAPTHR).
// ---------------------------------------------------------------------------
__global__ __launch_bounds__(512, 2)
void k_decode(const float* __restrict__ depot_xy,
              const float* __restrict__ customer_xy,
              const float* __restrict__ demand,
              const float* __restrict__ node_emb,
              const float* __restrict__ graph_emb,
              const float* __restrict__ Wk1,
              const float* __restrict__ Wv,
              const float* __restrict__ Wq_fixed,
              const float* __restrict__ Wq_step,
              const double* __restrict__ M64,
              const float* __restrict__ M32,
              float* __restrict__ out)          // [2*B]: cost then ll
{
    __shared__ float  sKs[NN * E_];             // 51.7 KB Kstep rows fp32
    __shared__ float  sV [NN * E_];             // 51.7 KB V rows fp32
    __shared__ double sU[2224];                 // union scratch 17.8 KB
    __shared__ double sQfix64[E_];
    __shared__ double sWqD64[E_];
    __shared__ float  sQfix32[E_];
    __shared__ float  sWqD32[E_];
    __shared__ float  sInvS[8];
    __shared__ float  sCoord[2 * NN];
    __shared__ float  sDem[NC];
    __shared__ float  sD;
    __shared__ double sCost, sLL;
    __shared__ float  sPosX, sPosY;
    __shared__ int    sPrev, sMaskDepot, sTrig, sOvf;
    __shared__ unsigned long long sVis0, sVis1;

    // fast fp32 views (overlay the fp64 fallback scratch)
    float* fSc   = (float*)sU;          // [8][104] exp-scores (pads 101..103)
    float* fPart = (float*)sU + 832;    // [4][128] glimpse partials
    float* fPx   = (float*)sU + 1344;   // [4][128] logit partials
    // fallback fp64 views (not live at same time as fSc/fPart/fPx)
    double* dUZ = sU;                   // [128][8] u1 then z
    double* dSc = sU + 1024;            // [8][101] scores -> weights
    double* dQ1 = sU + 1832;            // [128] q1, later xd[101]
    double* dGl = sU + 1960;            // [128]
    double* dVg = sU + 2088;            // [128]

    const int b      = blockIdx.x;
    const int tid    = threadIdx.x;
    const int lane   = tid & 63;
    const int h      = __builtin_amdgcn_readfirstlane(tid >> 6);   // head 0..7
    const int k1     = lane + 64;                                  // 2nd node
    const int k_lane = tid & 127;
    const int q2u    = __builtin_amdgcn_readfirstlane(tid >> 7);   // 0..3
    const int e0     = q2u * 32;
    const int kb     = q2u * 26;

    const float* emb = node_emb + (size_t)b * NN * E_;

    // ---------------- prologue ----------------
    if (tid < E_) {
        const float* ge = graph_emb + (size_t)b * E_;
        double acc = 0.0;
        for (int g = 0; g < E_; ++g)
            acc += (double)ge[g] * (double)Wq_fixed[g * E_ + tid];
        sQfix64[tid] = acc;
        sQfix32[tid] = (float)acc;
        sWqD64[tid]  = (double)Wq_step[128 * E_ + tid];
        sWqD32[tid]  = Wq_step[128 * E_ + tid];
    }
    if (tid < 2 * NN) {
        int k = tid >> 1, xy = tid & 1;
        sCoord[tid] = (k == 0) ? depot_xy[(size_t)b * 2 + xy]
                               : customer_xy[((size_t)b * NC + (k - 1)) * 2 + xy];
    }
    if (tid < NC) sDem[tid] = demand[(size_t)b * NC + tid];
    if (tid == 0) {
        sD = 1.f; sPrev = 0; sVis0 = 0ull; sVis1 = 0ull;
        sMaskDepot = 1; sCost = 0.0; sLL = 0.0; sTrig = 0; sOvf = 0;
        sPosX = depot_xy[(size_t)b * 2 + 0];
        sPosY = depot_xy[(size_t)b * 2 + 1];
    }

    // V and Kstep into LDS (fp32, float4 over columns)
    for (int idx = tid; idx < NN * 32; idx += 512) {
        int k  = idx >> 5;
        int e4 = (idx & 31) * 4;
        const float* er = emb + (size_t)k * E_;
        float4 aV = {0.f, 0.f, 0.f, 0.f};
        float4 aK = {0.f, 0.f, 0.f, 0.f};
        for (int g = 0; g < E_; ++g) {
            float eg = er[g];
            float4 wv = *(const float4*)(Wv      + (size_t)g * E_ + e4);
            float4 wq = *(const float4*)(Wq_step + (size_t)g * E_ + e4);
            aV.x += eg * wv.x; aV.y += eg * wv.y;
            aV.z += eg * wv.z; aV.w += eg * wv.w;
            aK.x += eg * wq.x; aK.y += eg * wq.y;
            aK.z += eg * wq.z; aK.w += eg * wq.w;
        }
        *(float4*)(sV  + (size_t)k * E_ + e4) = aV;
        *(float4*)(sKs + (size_t)k * E_ + e4) = aK;
    }

    // Per-wave K1h fragment (head h, nodes k=lane and k=lane+64)
    float rA[32];
#pragma unroll
    for (int j = 0; j < 32; ++j) rA[j] = 0.f;
    {
        const float* er0 = emb + (size_t)lane * E_;
        const float* er1 = emb + (size_t)((k1 < NN) ? k1 : lane) * E_;
        const float  e1s = (k1 < NN) ? 1.f : 0.f;
        const float* w1b = Wk1 + h * 16;
        for (int g = 0; g < E_; ++g) {
            float a0 = er0[g];
            float a1 = er1[g] * e1s;
            const float* w1 = w1b + (size_t)g * E_;
#pragma unroll
            for (int d = 0; d < 16; ++d) {
                rA[d]      += a0 * w1[d];
                rA[16 + d] += a1 * w1[d];
            }
        }
    }

    // K2t chunk (32 cols) into registers
    float rK2[32];
#pragma unroll
    for (int j = 0; j < 32; ++j) rK2[j] = 0.f;
    if (k_lane < NN) {
        const float* er = emb + (size_t)k_lane * E_;
        for (int g = 0; g < E_; ++g) {
            float eg = er[g];
            const float* mm = M32 + (size_t)g * E_ + e0;
#pragma unroll
            for (int j = 0; j < 32; ++j) rK2[j] += eg * mm[j];
        }
    }
    __syncthreads();

    // ---------------- sequential decode loop ----------------
    for (int t = 0; t < T_; ++t) {
        // ---- B (per-wave): q1 slice + scores + exp + head sum ----
        {
            int prev = sPrev;
            float Dv = sD;
            int d_ = h * 16 + (lane & 15);
            float q1v = (sQfix32[d_] + sKs[(size_t)prev * E_ + d_]
                         + Dv * sWqD32[d_]) * 0.25f;

            unsigned long long v0 = sVis0, v1 = sVis1;
            bool mk0, mk1;
            if (lane == 0) mk0 = (sMaskDepot != 0);
            else {
                int c = lane - 1;   // 0..62 -> always in sVis0
                mk0 = ((v0 >> c) & 1ull) || (sDem[c] > Dv);
            }
            if (k1 < NN) {
                int c = k1 - 1;     // 63..99
                bool vis = (c < 64) ? ((v0 >> c) & 1ull)
                                    : ((v1 >> (c - 64)) & 1ull);
                mk1 = vis || (sDem[c] > Dv);
            } else mk1 = true;

            float s0 = 0.f, s1 = 0.f;
#pragma unroll
            for (int d = 0; d < 16; ++d) {
                float qd = rdlane(q1v, d);
                s0 += rA[d] * qd;
                s1 += rA[16 + d] * qd;
            }
            bool ovf = (!mk0 && s0 > 80.f) || (!mk1 && s1 > 80.f);
            if (__any(ovf)) { if (lane == 0) sOvf = 1; }
            float w0 = mk0 ? 0.f : expf(fminf(s0, 80.f));
            float w1 = mk1 ? 0.f : expf(fminf(s1, 80.f));
            fSc[h * 104 + lane] = w0;
            if (k1 < 104) fSc[h * 104 + k1] = w1;
            float wsum = w0 + w1;
#pragma unroll
            for (int m = 32; m >= 1; m >>= 1) wsum += __shfl_xor(wsum, m);
            if (lane == 0) sInvS[h] = 1.0f / wsum;
        }
        __syncthreads();

        // ---- C: glimpse partials over 4 k-chunks (LDS sV) ----
        {
            int e = k_lane, hh = e >> 4;
            const float* sc = fSc + hh * 104 + kb;
            const float* vv = sV + (size_t)kb * E_ + e;
            float p = 0.f;
#pragma unroll
            for (int j = 0; j < 26; ++j) p += sc[j] * vv[j * E_];
            fPart[q2u * E_ + e] = p;
        }
        __syncthreads();

        // ---- D: logits via readlane dot (normalized glimpse in-flight) ----
        {
            int ee = e0 + (tid & 31);
            float glv = (fPart[ee] + fPart[128 + ee] + fPart[256 + ee]
                         + fPart[384 + ee]) * sInvS[ee >> 4];
            float x = 0.f;
#pragma unroll
            for (int j = 0; j < 32; ++j) x += rK2[j] * rdlane(glv, j);
            if (k_lane < NN) fPx[q2u * E_ + k_lane] = x;
        }
        __syncthreads();

        // ---- E: top-2 argmax (pre-tanh), gap test, commit-or-trigger ----
        if (tid < 64) {
            int kA = tid, kB = tid + 64;
            float xA = (fPx[kA] + fPx[128 + kA] + fPx[256 + kA] + fPx[384 + kA]) * INVSQE;
            bool mk1;
            if (kA == 0) mk1 = (sMaskDepot != 0);
            else {
                int c = kA - 1;
                bool vis = (c < 64) ? ((sVis0 >> c) & 1ull) : ((sVis1 >> (c - 64)) & 1ull);
                mk1 = vis || (sDem[c] > sD);
            }
            float xB = -3.0e38f; bool mk2 = true;
            if (kB < NN) {
                xB = (fPx[kB] + fPx[128 + kB] + fPx[256 + kB] + fPx[384 + kB]) * INVSQE;
                int c = kB - 1;
                bool vis = (c < 64) ? ((sVis0 >> c) & 1ull) : ((sVis1 >> (c - 64)) & 1ull);
                mk2 = vis || (sDem[c] > sD);
            }
            float a1v = mk1 ? -3.0e38f : xA;
            float a2v = mk2 ? -3.0e38f : xB;
            float m1, m2; int mi;
            if (a2v > a1v) { m1 = a2v; m2 = a1v; mi = kB; }
            else           { m1 = a1v; m2 = a2v; mi = kA; }
            float ls = 0.f;
            if (!mk1)              ls += expf(10.f * tanhf(xA));
            if (kB < NN && !mk2)   ls += expf(10.f * tanhf(xB));
#pragma unroll
            for (int off = 32; off > 0; off >>= 1) {
                float om1 = __shfl_xor(m1, off);
                float om2 = __shfl_xor(m2, off);
                float os  = __shfl_xor(ls, off);
                int   omi = __shfl_xor(mi, off);
                ls += os;
                if (om1 > m1 || (om1 == m1 && omi < mi)) {
                    m2 = fmaxf(m1, om2); m1 = om1; mi = omi;
                } else {
                    m2 = fmaxf(m2, om1);
                }
            }
            if (tid == 0) {
                float gap = m1 - m2;
                bool trig = !(gap >= GAPTHR) || (sOvf != 0);   // NaN-safe
                sOvf = 0;
                if (trig) {
                    sTrig = 1;
                } else {
                    float lsel = 10.f * tanhf(m1);
                    float logp = lsel - logf(ls);
                    int nxt = mi;
                    sLL += (double)logp;
                    bool isdep = (nxt == 0);
                    if (isdep) {
                        sD = 1.0f;
                    } else {
                        int c = nxt - 1;
                        sD = sD - sDem[c];
                        if (c < 64) sVis0 |= (1ull << c);
                        else        sVis1 |= (1ull << (c - 64));
                    }
                    bool allv = (sVis0 == 0xFFFFFFFFFFFFFFFFull) &&
                                (sVis1 == 0x0000000FFFFFFFFFull);
                    sMaskDepot = (isdep && !allv) ? 1 : 0;
                    sPrev = nxt;
                    float cx = sCoord[2 * nxt], cy = sCoord[2 * nxt + 1];
                    double dx = (double)cx - (double)sPosX;
                    double dy = (double)cy - (double)sPosY;
                    sCost += sqrt(dx * dx + dy * dy + 1e-10);
                    sPosX = cx; sPosY = cy;
                }
            }
        }
        __syncthreads();

        // ---- Fallback: exact fp64 recompute of this step (rare) ----
        if (sTrig) {
            // F0: q1d
            if (tid < E_) {
                const float* ep = emb + (size_t)sPrev * E_;
                double ks = 0.0;
                for (int g = 0; g < E_; ++g)
                    ks += (double)ep[g] * (double)Wq_step[(size_t)g * E_ + tid];
                dQ1[tid] = (sQfix64[tid] + ks + (double)sD * sWqD64[tid]) * 0.25;
            }
            __syncthreads();
            // F1: u1[g][h]
            for (int idx = tid; idx < 1024; idx += 512) {
                int g = idx >> 3, hh = idx & 7;
                double u = 0.0;
#pragma unroll 4
                for (int d = 0; d < 16; ++d)
                    u += dQ1[hh * 16 + d] * (double)Wk1[(size_t)g * E_ + hh * 16 + d];
                dUZ[idx] = u;
            }
            __syncthreads();
            // F2: scores
            for (int idx = tid; idx < 1024; idx += 512) {
                int k = idx & 127, hh = idx >> 7;
                if (k < NN) {
                    bool mk;
                    if (k == 0) mk = (sMaskDepot != 0);
                    else {
                        int c = k - 1;
                        bool vis = (c < 64) ? ((sVis0 >> c) & 1ull) : ((sVis1 >> (c - 64)) & 1ull);
                        mk = vis || (sDem[c] > sD);
                    }
                    if (mk) dSc[hh * NN + k] = NEGV;
                    else {
                        const float* ek = emb + (size_t)k * E_;
                        double s = 0.0;
                        for (int g = 0; g < E_; ++g)
                            s += (double)ek[g] * dUZ[g * 8 + hh];
                        dSc[hh * NN + k] = s;
                    }
                }
            }
            __syncthreads();
            // F3: per-head softmax (wave hh), normalized weights in place
            {
                int hh = tid >> 6, ln = tid & 63;
                int kA = ln, kB = ln + 64;
                double v1 = dSc[hh * NN + kA];
                double v2 = (kB < NN) ? dSc[hh * NN + kB] : -1.0e300;
                double m = fmax(v1, v2);
#pragma unroll
                for (int off = 32; off > 0; off >>= 1)
                    m = fmax(m, __shfl_xor(m, off));
                double e1 = exp(v1 - m);
                double e2 = (kB < NN) ? exp(v2 - m) : 0.0;
                double s = e1 + e2;
#pragma unroll
                for (int off = 32; off > 0; off >>= 1)
                    s += __shfl_xor(s, off);
                double inv = 1.0 / s;
                dSc[hh * NN + kA] = e1 * inv;
                if (kB < NN) dSc[hh * NN + kB] = e2 * inv;
            }
            __syncthreads();
            // F4: z[g][h] = sum_k w[h][k] emb[k][g]
            for (int idx = tid; idx < 1024; idx += 512) {
                int g = idx >> 3, hh = idx & 7;
                double z = 0.0;
                for (int k = 0; k < NN; ++k)
                    z += dSc[hh * NN + k] * (double)emb[(size_t)k * E_ + g];
                dUZ[idx] = z;
            }
            __syncthreads();
            // F5: glimpse
            if (tid < E_) {
                int hh = tid >> 4;
                double g2 = 0.0;
                for (int g = 0; g < E_; ++g)
                    g2 += dUZ[g * 8 + hh] * (double)Wv[(size_t)g * E_ + tid];
                dGl[tid] = g2;
            }
            __syncthreads();
            // F6: vg = M64 @ glimpse
            if (tid < E_) {
                double v = 0.0;
                for (int e = 0; e < E_; ++e)
                    v += dGl[e] * M64[(size_t)tid * E_ + e];
                dVg[tid] = v;
            }
            __syncthreads();
            // F7: xd[k] (reuse dQ1)
            if (tid < NN) {
                const float* ek = emb + (size_t)tid * E_;
                double x = 0.0;
                for (int g = 0; g < E_; ++g)
                    x += (double)ek[g] * dVg[g];
                dQ1[tid] = x * INVSQED;
            }
            __syncthreads();
            // F8: fp64 argmax + LSE + commit
            if (tid < 64) {
                int kA = tid, kB = tid + 64;
                double x1 = dQ1[kA];
                bool mk1;
                if (kA == 0) mk1 = (sMaskDepot != 0);
                else {
                    int c = kA - 1;
                    bool vis = (c < 64) ? ((sVis0 >> c) & 1ull) : ((sVis1 >> (c - 64)) & 1ull);
                    mk1 = vis || (sDem[c] > sD);
                }
                double x2 = 0.0; bool mk2 = true;
                if (kB < NN) {
                    x2 = dQ1[kB];
                    int c = kB - 1;
                    bool vis = (c < 64) ? ((sVis0 >> c) & 1ull) : ((sVis1 >> (c - 64)) & 1ull);
                    mk2 = vis || (sDem[c] > sD);
                }
                double a1 = mk1 ? -1.0e300 : x1;
                double a2 = (kB < NN && !mk2) ? x2 : -1.0e300;
                double mv; int mi;
                if (a1 >= a2) { mv = a1; mi = kA; } else { mv = a2; mi = kB; }
#pragma unroll
                for (int off = 32; off > 0; off >>= 1) {
                    double ov = __shfl_xor(mv, off);
                    int    oi = __shfl_xor(mi, off);
                    if (ov > mv || (ov == mv && oi < mi)) { mv = ov; mi = oi; }
                }
                double lmax = 10.0 * tanh(mv);
                double l1 = mk1 ? NEGV : 10.0 * tanh(x1);
                double l2 = (kB < NN) ? (mk2 ? NEGV : 10.0 * tanh(x2)) : 0.0;
                double s = exp(l1 - lmax) + ((kB < NN) ? exp(l2 - lmax) : 0.0);
#pragma unroll
                for (int off = 32; off > 0; off >>= 1)
                    s += __shfl_xor(s, off);
                if (tid == 0) {
                    int nxt = mi;
                    sLL += -log(s);
                    bool isdep = (nxt == 0);
                    if (isdep) {
                        sD = 1.0f;
                    } else {
                        int c = nxt - 1;
                        sD = sD - sDem[c];
                        if (c < 64) sVis0 |= (1ull << c);
                        else        sVis1 |= (1ull << (c - 64));
                    }
                    bool allv = (sVis0 == 0xFFFFFFFFFFFFFFFFull) &&
                                (sVis1 == 0x0000000FFFFFFFFFull);
                    sMaskDepot = (isdep && !allv) ? 1 : 0;
                    sPrev = nxt;
                    float cx = sCoord[2 * nxt], cy = sCoord[2 * nxt + 1];
                    double dx = (double)cx - (double)sPosX;
                    double dy = (double)cy - (double)sPosY;
                    sCost += sqrt(dx * dx + dy * dy + 1e-10);
                    sPosX = cx; sPosY = cy;
                    sTrig = 0;
                }
            }
            __syncthreads();
        }
    }

    if (tid == 0) {
        double dx = (double)sCoord[0] - (double)sPosX;
        double dy = (double)sCoord[1] - (double)sPosY;
        out[b]      = (float)(sCost + sqrt(dx * dx + dy * dy + 1e-10));
        out[B_ + b] = (float)sLL;
    }
}

// ---------------------------------------------------------------------------
extern "C" void kernel_launch(void* const* d_in, const int* in_sizes, int n_in,
                              void* d_out, int out_size, void* d_ws, size_t ws_size,
                              hipStream_t stream) {
    const float* depot = (const float*)d_in[0];
    const float* cust  = (const float*)d_in[1];
    const float* dem   = (const float*)d_in[2];
    const float* nemb  = (const float*)d_in[3];
    const float* gemb  = (const float*)d_in[4];
    const float* Wk1   = (const float*)d_in[5];
    const float* Wv    = (const float*)d_in[6];
    const float* Wk2   = (const float*)d_in[7];
    const float* Wqf   = (const float*)d_in[8];
    const float* Wout  = (const float*)d_in[9];
    const float* Wqs   = (const float*)d_in[10];
    float*  out = (float*)d_out;
    double* M64 = (double*)d_ws;                       // 128 KB
    float*  M32 = (float*)((char*)d_ws + 131072);      // 64 KB

    k_weights<<<dim3(128), dim3(128), 0, stream>>>(Wk2, Wout, M64, M32);
    k_decode <<<dim3(B_),  dim3(512), 0, stream>>>(depot, cust, dem, nemb, gemb,
                                                   Wk1, Wv, Wqf, Wqs, M64, M32, out);
}

// Round 15
// 3170.614 us; speedup vs baseline: 3.5881x; 1.1280x over previous
//
#include <hip/hip_runtime.h>
#include <math.h>

// Problem constants (match reference)
#define B_   1024
#define NC   100
#define NN   101          // N = NC + 1
#define E_   128
#define T_   202          // 2*N
#define NEGV   -1.0e9
#define GAPTHR 1.0e-3f    // decision guard band (round-14 proven)
#define INVSQE 0.08838834764831845f
#define INVSQED 0.08838834764831845

__device__ __forceinline__ float rdlane(float v, int l) {
    return __int_as_float(__builtin_amdgcn_readlane(__float_as_int(v), l));
}
// fast tanh via native exp (error ~few ulp; decisions use pre-tanh values,
// LL value error << 3.5 threshold)
__device__ __forceinline__ float fast_tanh(float x) {
    float xc = fminf(fmaxf(x, -15.f), 15.f);
    float e  = __expf(2.f * xc);
    return (e - 1.f) / (e + 1.f);
}

// ---------------------------------------------------------------------------
// kernel 0: M = Wk2 @ Wout^T (128x128) into ws as fp64 (fallback) + fp32 (fast)
// ---------------------------------------------------------------------------
__global__ void k_weights(const float* __restrict__ Wk2,
                          const float* __restrict__ Wout,
                          double* __restrict__ M64,
                          float* __restrict__ M32) {
    int g = blockIdx.x;   // 0..127
    int e = threadIdx.x;  // 0..127
    const float* w2 = Wk2 + g * E_;
    const float* wo = Wout + e * E_;
    double acc = 0.0;
#pragma unroll 8
    for (int f = 0; f < E_; ++f) acc += (double)w2[f] * (double)wo[f];
    M64[g * E_ + e] = acc;
    M32[g * E_ + e] = (float)acc;
}

// ---------------------------------------------------------------------------
// Main decoder. 1 block / batch element, 512 threads (8 waves).
// Round-14 structure with: (1) native __expf/__logf/fast_tanh in the fast
// path, (2) B+C fused into one barrier-free per-wave phase (softmax+glimpse
// are block-diagonal per head; intra-wave LDS write->read is FIFO-ordered),
// (3) 3-shuffle argmax butterfly + __any near-tie ballot. 3 barriers/step.
// Exact fp64 fallback on near-tie argmax (gap < GAPTHR) unchanged.
// ---------------------------------------------------------------------------
__global__ __launch_bounds__(512, 2)
void k_decode(const float* __restrict__ depot_xy,
              const float* __restrict__ customer_xy,
              const float* __restrict__ demand,
              const float* __restrict__ node_emb,
              const float* __restrict__ graph_emb,
              const float* __restrict__ Wk1,
              const float* __restrict__ Wv,
              const float* __restrict__ Wq_fixed,
              const float* __restrict__ Wq_step,
              const double* __restrict__ M64,
              const float* __restrict__ M32,
              float* __restrict__ out)          // [2*B]: cost then ll
{
    __shared__ float  sKs[NN * E_];             // 51.7 KB Kstep rows fp32
    __shared__ float  sV [NN * E_];             // 51.7 KB V rows fp32
    __shared__ double sU[2224];                 // union scratch 17.8 KB
    __shared__ double sQfix64[E_];
    __shared__ double sWqD64[E_];
    __shared__ float  sQfix32[E_];
    __shared__ float  sWqD32[E_];
    __shared__ float  sCoord[2 * NN];
    __shared__ float  sDem[NC];
    __shared__ float  sD;
    __shared__ double sCost, sLL;
    __shared__ float  sPosX, sPosY;
    __shared__ int    sPrev, sMaskDepot, sTrig, sOvf;
    __shared__ unsigned long long sVis0, sVis1;

    // fast fp32 views (overlay the fp64 fallback scratch)
    float* fSc = (float*)sU;            // [8][104] exp-scores (pads 101..103)
    float* gl  = (float*)sU + 832;      // [128] normalized glimpse
    float* fPx = (float*)sU + 960;      // [4][128] logit partials
    // fallback fp64 views (not live at same time as fast views)
    double* dUZ = sU;                   // [128][8] u1 then z
    double* dSc = sU + 1024;            // [8][101] scores -> weights
    double* dQ1 = sU + 1832;            // [128] q1, later xd[101]
    double* dGl = sU + 1960;            // [128]
    double* dVg = sU + 2088;            // [128]

    const int b      = blockIdx.x;
    const int tid    = threadIdx.x;
    const int lane   = tid & 63;
    const int h      = __builtin_amdgcn_readfirstlane(tid >> 6);   // head 0..7
    const int k1     = lane + 64;                                  // 2nd node
    const int k_lane = tid & 127;
    const int q2u    = __builtin_amdgcn_readfirstlane(tid >> 7);   // 0..3
    const int e0     = q2u * 32;

    const float* emb = node_emb + (size_t)b * NN * E_;

    // ---------------- prologue ----------------
    if (tid < E_) {
        const float* ge = graph_emb + (size_t)b * E_;
        double acc = 0.0;
        for (int g = 0; g < E_; ++g)
            acc += (double)ge[g] * (double)Wq_fixed[g * E_ + tid];
        sQfix64[tid] = acc;
        sQfix32[tid] = (float)acc;
        sWqD64[tid]  = (double)Wq_step[128 * E_ + tid];
        sWqD32[tid]  = Wq_step[128 * E_ + tid];
    }
    if (tid < 2 * NN) {
        int k = tid >> 1, xy = tid & 1;
        sCoord[tid] = (k == 0) ? depot_xy[(size_t)b * 2 + xy]
                               : customer_xy[((size_t)b * NC + (k - 1)) * 2 + xy];
    }
    if (tid < NC) sDem[tid] = demand[(size_t)b * NC + tid];
    if (tid == 0) {
        sD = 1.f; sPrev = 0; sVis0 = 0ull; sVis1 = 0ull;
        sMaskDepot = 1; sCost = 0.0; sLL = 0.0; sTrig = 0; sOvf = 0;
        sPosX = depot_xy[(size_t)b * 2 + 0];
        sPosY = depot_xy[(size_t)b * 2 + 1];
    }

    // V and Kstep into LDS (fp32, float4 over columns)
    for (int idx = tid; idx < NN * 32; idx += 512) {
        int k  = idx >> 5;
        int e4 = (idx & 31) * 4;
        const float* er = emb + (size_t)k * E_;
        float4 aV = {0.f, 0.f, 0.f, 0.f};
        float4 aK = {0.f, 0.f, 0.f, 0.f};
        for (int g = 0; g < E_; ++g) {
            float eg = er[g];
            float4 wv = *(const float4*)(Wv      + (size_t)g * E_ + e4);
            float4 wq = *(const float4*)(Wq_step + (size_t)g * E_ + e4);
            aV.x += eg * wv.x; aV.y += eg * wv.y;
            aV.z += eg * wv.z; aV.w += eg * wv.w;
            aK.x += eg * wq.x; aK.y += eg * wq.y;
            aK.z += eg * wq.z; aK.w += eg * wq.w;
        }
        *(float4*)(sV  + (size_t)k * E_ + e4) = aV;
        *(float4*)(sKs + (size_t)k * E_ + e4) = aK;
    }

    // Per-wave K1h fragment (head h, nodes k=lane and k=lane+64)
    float rA[32];
#pragma unroll
    for (int j = 0; j < 32; ++j) rA[j] = 0.f;
    {
        const float* er0 = emb + (size_t)lane * E_;
        const float* er1 = emb + (size_t)((k1 < NN) ? k1 : lane) * E_;
        const float  e1s = (k1 < NN) ? 1.f : 0.f;
        const float* w1b = Wk1 + h * 16;
        for (int g = 0; g < E_; ++g) {
            float a0 = er0[g];
            float a1 = er1[g] * e1s;
            const float* w1 = w1b + (size_t)g * E_;
#pragma unroll
            for (int d = 0; d < 16; ++d) {
                rA[d]      += a0 * w1[d];
                rA[16 + d] += a1 * w1[d];
            }
        }
    }

    // K2t chunk (32 cols) into registers
    float rK2[32];
#pragma unroll
    for (int j = 0; j < 32; ++j) rK2[j] = 0.f;
    if (k_lane < NN) {
        const float* er = emb + (size_t)k_lane * E_;
        for (int g = 0; g < E_; ++g) {
            float eg = er[g];
            const float* mm = M32 + (size_t)g * E_ + e0;
#pragma unroll
            for (int j = 0; j < 32; ++j) rK2[j] += eg * mm[j];
        }
    }
    __syncthreads();

    // ---------------- sequential decode loop ----------------
    for (int t = 0; t < T_; ++t) {
        // ---- BC (fused, per-wave; no internal barrier): scores -> exp
        //      -> (intra-wave LDS exchange) -> glimpse dims of head h ----
        {
            int prev = sPrev;
            float Dv = sD;
            int d_ = h * 16 + (lane & 15);
            float q1v = (sQfix32[d_] + sKs[(size_t)prev * E_ + d_]
                         + Dv * sWqD32[d_]) * 0.25f;

            unsigned long long v0 = sVis0, v1 = sVis1;
            bool mk0, mk1;
            if (lane == 0) mk0 = (sMaskDepot != 0);
            else {
                int c = lane - 1;   // 0..62 -> always in sVis0
                mk0 = ((v0 >> c) & 1ull) || (sDem[c] > Dv);
            }
            if (k1 < NN) {
                int c = k1 - 1;     // 63..99
                bool vis = (c < 64) ? ((v0 >> c) & 1ull)
                                    : ((v1 >> (c - 64)) & 1ull);
                mk1 = vis || (sDem[c] > Dv);
            } else mk1 = true;

            float s0a = 0.f, s0b = 0.f, s1a = 0.f, s1b = 0.f;
#pragma unroll
            for (int d = 0; d < 8; ++d) {
                float qd = rdlane(q1v, d);
                s0a += rA[d] * qd;
                s1a += rA[16 + d] * qd;
            }
#pragma unroll
            for (int d = 8; d < 16; ++d) {
                float qd = rdlane(q1v, d);
                s0b += rA[d] * qd;
                s1b += rA[16 + d] * qd;
            }
            float s0 = s0a + s0b, s1 = s1a + s1b;
            bool ovf = (!mk0 && s0 > 80.f) || (!mk1 && s1 > 80.f);
            if (__any(ovf)) { if (lane == 0) sOvf = 1; }
            float w0 = mk0 ? 0.f : __expf(fminf(s0, 80.f));
            float w1 = mk1 ? 0.f : __expf(fminf(s1, 80.f));
            fSc[h * 104 + lane] = w0;
            if (k1 < 104) fSc[h * 104 + k1] = w1;

            __builtin_amdgcn_wave_barrier();  // pin write->read program order

            // consume own head's weights: chunk cq4 = lane>>4, 26 nodes each
            int cq4 = lane >> 4;
            const float* sc = fSc + h * 104 + cq4 * 26;
            const float* vv = sV + (size_t)(cq4 * 26) * E_ + d_;
            float p = 0.f, ssum = 0.f;
#pragma unroll
            for (int j = 0; j < 26; ++j) {
                float wgt = sc[j];              // pads (101..103) are 0
                p    += wgt * vv[(size_t)j * E_];
                ssum += wgt;
            }
            p    += __shfl_xor(p, 16);
            ssum += __shfl_xor(ssum, 16);
            p    += __shfl_xor(p, 32);
            ssum += __shfl_xor(ssum, 32);
            if (lane < 16) gl[d_] = p * (1.0f / ssum);
        }
        __syncthreads();

        // ---- D: logits via readlane dot over normalized glimpse ----
        {
            int ee = e0 + (tid & 31);
            float glv = gl[ee];
            float xa = 0.f, xb = 0.f, xc = 0.f, xd = 0.f;
#pragma unroll
            for (int j = 0; j < 8; ++j)   xa += rK2[j] * rdlane(glv, j);
#pragma unroll
            for (int j = 8; j < 16; ++j)  xb += rK2[j] * rdlane(glv, j);
#pragma unroll
            for (int j = 16; j < 24; ++j) xc += rK2[j] * rdlane(glv, j);
#pragma unroll
            for (int j = 24; j < 32; ++j) xd += rK2[j] * rdlane(glv, j);
            if (k_lane < NN) fPx[q2u * E_ + k_lane] = (xa + xb) + (xc + xd);
        }
        __syncthreads();

        // ---- E: argmax (3-shuffle butterfly) + __any near-tie + commit ----
        if (tid < 64) {
            int kA = tid, kB = tid + 64;
            float xA = (fPx[kA] + fPx[128 + kA] + fPx[256 + kA] + fPx[384 + kA]) * INVSQE;
            bool mk1;
            if (kA == 0) mk1 = (sMaskDepot != 0);
            else {
                int c = kA - 1;
                bool vis = (c < 64) ? ((sVis0 >> c) & 1ull) : ((sVis1 >> (c - 64)) & 1ull);
                mk1 = vis || (sDem[c] > sD);
            }
            float xB = -3.0e38f; bool mk2 = true;
            if (kB < NN) {
                xB = (fPx[kB] + fPx[128 + kB] + fPx[256 + kB] + fPx[384 + kB]) * INVSQE;
                int c = kB - 1;
                bool vis = (c < 64) ? ((sVis0 >> c) & 1ull) : ((sVis1 >> (c - 64)) & 1ull);
                mk2 = vis || (sDem[c] > sD);
            }
            float a1v = mk1 ? -3.0e38f : xA;
            float a2v = mk2 ? -3.0e38f : xB;
            float m1; int mi;
            if (a2v > a1v) { m1 = a2v; mi = kB; }
            else           { m1 = a1v; mi = kA; }
            float ls = 0.f;
            if (!mk1)              ls += __expf(10.f * fast_tanh(xA));
            if (kB < NN && !mk2)   ls += __expf(10.f * fast_tanh(xB));
#pragma unroll
            for (int off = 32; off > 0; off >>= 1) {
                float om1 = __shfl_xor(m1, off);
                int   omi = __shfl_xor(mi, off);
                ls += __shfl_xor(ls, off);
                if (om1 > m1 || (om1 == m1 && omi < mi)) { m1 = om1; mi = omi; }
            }
            // near-tie ballot: exists another unmasked value > m1 - GAPTHR
            // (equivalent to second-max gap < GAPTHR)
            bool near = false;
            if (!mk1 && kA != mi && a1v > m1 - GAPTHR) near = true;
            if (!mk2 && kB != mi && a2v > m1 - GAPTHR) near = true;
            bool trigAny = __any(near);
            if (tid == 0) {
                bool trig = trigAny || (sOvf != 0) || !(m1 == m1);   // NaN-safe
                sOvf = 0;
                if (trig) {
                    sTrig = 1;
                } else {
                    float lsel = 10.f * fast_tanh(m1);
                    float logp = lsel - __logf(ls);
                    int nxt = mi;
                    sLL += (double)logp;
                    bool isdep = (nxt == 0);
                    if (isdep) {
                        sD = 1.0f;
                    } else {
                        int c = nxt - 1;
                        sD = sD - sDem[c];
                        if (c < 64) sVis0 |= (1ull << c);
                        else        sVis1 |= (1ull << (c - 64));
                    }
                    bool allv = (sVis0 == 0xFFFFFFFFFFFFFFFFull) &&
                                (sVis1 == 0x0000000FFFFFFFFFull);
                    sMaskDepot = (isdep && !allv) ? 1 : 0;
                    sPrev = nxt;
                    float cx = sCoord[2 * nxt], cy = sCoord[2 * nxt + 1];
                    double dx = (double)cx - (double)sPosX;
                    double dy = (double)cy - (double)sPosY;
                    sCost += sqrt(dx * dx + dy * dy + 1e-10);
                    sPosX = cx; sPosY = cy;
                }
            }
        }
        __syncthreads();

        // ---- Fallback: exact fp64 recompute of this step (rare) ----
        if (sTrig) {
            // F0: q1d
            if (tid < E_) {
                const float* ep = emb + (size_t)sPrev * E_;
                double ks = 0.0;
                for (int g = 0; g < E_; ++g)
                    ks += (double)ep[g] * (double)Wq_step[(size_t)g * E_ + tid];
                dQ1[tid] = (sQfix64[tid] + ks + (double)sD * sWqD64[tid]) * 0.25;
            }
            __syncthreads();
            // F1: u1[g][h]
            for (int idx = tid; idx < 1024; idx += 512) {
                int g = idx >> 3, hh = idx & 7;
                double u = 0.0;
#pragma unroll 4
                for (int d = 0; d < 16; ++d)
                    u += dQ1[hh * 16 + d] * (double)Wk1[(size_t)g * E_ + hh * 16 + d];
                dUZ[idx] = u;
            }
            __syncthreads();
            // F2: scores
            for (int idx = tid; idx < 1024; idx += 512) {
                int k = idx & 127, hh = idx >> 7;
                if (k < NN) {
                    bool mk;
                    if (k == 0) mk = (sMaskDepot != 0);
                    else {
                        int c = k - 1;
                        bool vis = (c < 64) ? ((sVis0 >> c) & 1ull) : ((sVis1 >> (c - 64)) & 1ull);
                        mk = vis || (sDem[c] > sD);
                    }
                    if (mk) dSc[hh * NN + k] = NEGV;
                    else {
                        const float* ek = emb + (size_t)k * E_;
                        double s = 0.0;
                        for (int g = 0; g < E_; ++g)
                            s += (double)ek[g] * dUZ[g * 8 + hh];
                        dSc[hh * NN + k] = s;
                    }
                }
            }
            __syncthreads();
            // F3: per-head softmax (wave hh), normalized weights in place
            {
                int hh = tid >> 6, ln = tid & 63;
                int kA = ln, kB = ln + 64;
                double v1 = dSc[hh * NN + kA];
                double v2 = (kB < NN) ? dSc[hh * NN + kB] : -1.0e300;
                double m = fmax(v1, v2);
#pragma unroll
                for (int off = 32; off > 0; off >>= 1)
                    m = fmax(m, __shfl_xor(m, off));
                double e1 = exp(v1 - m);
                double e2 = (kB < NN) ? exp(v2 - m) : 0.0;
                double s = e1 + e2;
#pragma unroll
                for (int off = 32; off > 0; off >>= 1)
                    s += __shfl_xor(s, off);
                double inv = 1.0 / s;
                dSc[hh * NN + kA] = e1 * inv;
                if (kB < NN) dSc[hh * NN + kB] = e2 * inv;
            }
            __syncthreads();
            // F4: z[g][h] = sum_k w[h][k] emb[k][g]
            for (int idx = tid; idx < 1024; idx += 512) {
                int g = idx >> 3, hh = idx & 7;
                double z = 0.0;
                for (int k = 0; k < NN; ++k)
                    z += dSc[hh * NN + k] * (double)emb[(size_t)k * E_ + g];
                dUZ[idx] = z;
            }
            __syncthreads();
            // F5: glimpse
            if (tid < E_) {
                int hh = tid >> 4;
                double g2 = 0.0;
                for (int g = 0; g < E_; ++g)
                    g2 += dUZ[g * 8 + hh] * (double)Wv[(size_t)g * E_ + tid];
                dGl[tid] = g2;
            }
            __syncthreads();
            // F6: vg = M64 @ glimpse
            if (tid < E_) {
                double v = 0.0;
                for (int e = 0; e < E_; ++e)
                    v += dGl[e] * M64[(size_t)tid * E_ + e];
                dVg[tid] = v;
            }
            __syncthreads();
            // F7: xd[k] (reuse dQ1)
            if (tid < NN) {
                const float* ek = emb + (size_t)tid * E_;
                double x = 0.0;
                for (int g = 0; g < E_; ++g)
                    x += (double)ek[g] * dVg[g];
                dQ1[tid] = x * INVSQED;
            }
            __syncthreads();
            // F8: fp64 argmax + LSE + commit
            if (tid < 64) {
                int kA = tid, kB = tid + 64;
                double x1 = dQ1[kA];
                bool mk1;
                if (kA == 0) mk1 = (sMaskDepot != 0);
                else {
                    int c = kA - 1;
                    bool vis = (c < 64) ? ((sVis0 >> c) & 1ull) : ((sVis1 >> (c - 64)) & 1ull);
                    mk1 = vis || (sDem[c] > sD);
                }
                double x2 = 0.0; bool mk2 = true;
                if (kB < NN) {
                    x2 = dQ1[kB];
                    int c = kB - 1;
                    bool vis = (c < 64) ? ((sVis0 >> c) & 1ull) : ((sVis1 >> (c - 64)) & 1ull);
                    mk2 = vis || (sDem[c] > sD);
                }
                double a1 = mk1 ? -1.0e300 : x1;
                double a2 = (kB < NN && !mk2) ? x2 : -1.0e300;
                double mv; int mi;
                if (a1 >= a2) { mv = a1; mi = kA; } else { mv = a2; mi = kB; }
#pragma unroll
                for (int off = 32; off > 0; off >>= 1) {
                    double ov = __shfl_xor(mv, off);
                    int    oi = __shfl_xor(mi, off);
                    if (ov > mv || (ov == mv && oi < mi)) { mv = ov; mi = oi; }
                }
                double lmax = 10.0 * tanh(mv);
                double l1 = mk1 ? NEGV : 10.0 * tanh(x1);
                double l2 = (kB < NN) ? (mk2 ? NEGV : 10.0 * tanh(x2)) : 0.0;
                double s = exp(l1 - lmax) + ((kB < NN) ? exp(l2 - lmax) : 0.0);
#pragma unroll
                for (int off = 32; off > 0; off >>= 1)
                    s += __shfl_xor(s, off);
                if (tid == 0) {
                    int nxt = mi;
                    sLL += -log(s);
                    bool isdep = (nxt == 0);
                    if (isdep) {
                        sD = 1.0f;
                    } else {
                        int c = nxt - 1;
                        sD = sD - sDem[c];
                        if (c < 64) sVis0 |= (1ull << c);
                        else        sVis1 |= (1ull << (c - 64));
                    }
                    bool allv = (sVis0 == 0xFFFFFFFFFFFFFFFFull) &&
                                (sVis1 == 0x0000000FFFFFFFFFull);
                    sMaskDepot = (isdep && !allv) ? 1 : 0;
                    sPrev = nxt;
                    float cx = sCoord[2 * nxt], cy = sCoord[2 * nxt + 1];
                    double dx = (double)cx - (double)sPosX;
                    double dy = (double)cy - (double)sPosY;
                    sCost += sqrt(dx * dx + dy * dy + 1e-10);
                    sPosX = cx; sPosY = cy;
                    sTrig = 0;
                }
            }
            __syncthreads();
        }
    }

    if (tid == 0) {
        double dx = (double)sCoord[0] - (double)sPosX;
        double dy = (double)sCoord[1] - (double)sPosY;
        out[b]      = (float)(sCost + sqrt(dx * dx + dy * dy + 1e-10));
        out[B_ + b] = (float)sLL;
    }
}

// ---------------------------------------------------------------------------
extern "C" void kernel_launch(void* const* d_in, const int* in_sizes, int n_in,
                              void* d_out, int out_size, void* d_ws, size_t ws_size,
                              hipStream_t stream) {
    const float* depot = (const float*)d_in[0];
    const float* cust  = (const float*)d_in[1];
    const float* dem   = (const float*)d_in[2];
    const float* nemb  = (const float*)d_in[3];
    const float* gemb  = (const float*)d_in[4];
    const float* Wk1   = (const float*)d_in[5];
    const float* Wv    = (const float*)d_in[6];
    const float* Wk2   = (const float*)d_in[7];
    const float* Wqf   = (const float*)d_in[8];
    const float* Wout  = (const float*)d_in[9];
    const float* Wqs   = (const float*)d_in[10];
    float*  out = (float*)d_out;
    double* M64 = (double*)d_ws;                       // 128 KB
    float*  M32 = (float*)((char*)d_ws + 131072);      // 64 KB

    k_weights<<<dim3(128), dim3(128), 0, stream>>>(Wk2, Wout, M64, M32);
    k_decode <<<dim3(B_),  dim3(512), 0, stream>>>(depot, cust, dem, nemb, gemb,
                                                   Wk1, Wv, Wqf, Wqs, M64, M32, out);
}